// Round 2
// baseline (421.031 us; speedup 1.0000x reference)
//
#include <hip/hip_runtime.h>
#include <stdint.h>

#define B_    2048
#define N_    64
#define C_    256
#define C2_   128
#define H_    8
#define NW_   64
#define NPOS  225   // 15*15

typedef __attribute__((ext_vector_type(8))) short short8;
typedef __attribute__((ext_vector_type(4))) float float4v;

union U8 { unsigned u[4]; short8 s; };

// Module-scope scratch (graph-safe; rewritten by prep kernels every launch).
__device__ float g_scale[H_];                    // exp(min(logit_scale, log100))
__device__ float g_t8[NPOS][H_];                 // CPB-MLP table
__device__ __align__(16) float g_sb[NW_ * H_ * N_ * N_];  // NATURAL [w][h][q row][k col]
__device__ unsigned short g_wt[4][2][C2_][C2_];  // bf16 W^T: [proj][half][d][c]

__device__ __forceinline__ float b2f(unsigned short u) {
  return __uint_as_float(((unsigned int)u) << 16);
}
__device__ __forceinline__ unsigned short f2b(float f) {
  unsigned int u = __float_as_uint(f);
  u += 0x7fffu + ((u >> 16) & 1u);    // RNE
  return (unsigned short)(u >> 16);
}

// --- prep 1: CPB-MLP table + per-head scale (1 block, LDS-staged weights) ----
__global__ __launch_bounds__(256) void k_prep1(
    const float* __restrict__ tbl, const float* __restrict__ w1,
    const float* __restrict__ b1, const float* __restrict__ w2,
    const float* __restrict__ ls) {
  __shared__ float sw1[256], sb1[128], sw2[1024];
  const int t = threadIdx.x;
  sw1[t] = w1[t];
  if (t < 128) sb1[t] = b1[t];
#pragma unroll
  for (int it = 0; it < 4; ++it) sw2[it * 256 + t] = w2[it * 256 + t];
  __syncthreads();
  if (t < NPOS) {
    float a0 = tbl[2 * t], a1 = tbl[2 * t + 1];
    float acc[H_];
#pragma unroll
    for (int h = 0; h < H_; ++h) acc[h] = 0.f;
    for (int j = 0; j < 128; ++j) {
      float hid = fmaxf(a0 * sw1[j] + a1 * sw1[128 + j] + sb1[j], 0.f);
#pragma unroll
      for (int h = 0; h < H_; ++h) acc[h] += hid * sw2[j * H_ + h];
    }
#pragma unroll
    for (int h = 0; h < H_; ++h) g_t8[t][h] = acc[h];
  }
  if (t < H_) g_scale[t] = __expf(fminf(ls[t], 4.6051702f));
}

// --- prep 2: 16*sigmoid(bias)+mask, NATURAL order [w][h][q][k] ---------------
__global__ __launch_bounds__(256) void k_prep2(
    const float* __restrict__ mask, const int* __restrict__ rpi) {
  const int base = blockIdx.x * 1024;
#pragma unroll
  for (int it = 0; it < 4; ++it) {
    int idx = base + it * 256 + threadIdx.x;     // [0, 2M)
    int j  = idx & 63;            // col (k) — fastest => coalesced reads/writes
    int i  = (idx >> 6) & 63;     // row (q)
    int h  = (idx >> 12) & 7;
    int wd = idx >> 15;
    float v = g_t8[rpi[i * 64 + j]][h];
    g_sb[idx] = 16.f / (1.f + __expf(-v)) + mask[wd * 4096 + i * 64 + j];
  }
}

// --- prep 3: weights -> bf16 transposed via LDS (coalesced both sides) -------
__global__ __launch_bounds__(256) void k_prepw(
    const float* __restrict__ qw, const float* __restrict__ kw,
    const float* __restrict__ vw, const float* __restrict__ pw) {
  __shared__ unsigned short lt[128 * 132];
  const int t = threadIdx.x;
  const int p = blockIdx.x >> 1, s = blockIdx.x & 1;
  const float* src = (p == 0 ? qw : p == 1 ? kw : p == 2 ? vw : pw) + s * (C2_ * C2_);
#pragma unroll
  for (int it = 0; it < 64; ++it) {
    int e = it * 256 + t;         // e = c*128 + d, coalesced read
    int c = e >> 7, d = e & 127;
    lt[d * 132 + c] = f2b(src[e]);
  }
  __syncthreads();
#pragma unroll
  for (int it = 0; it < 64; ++it) {
    int e = it * 256 + t;         // e = d*128 + c, coalesced write
    int d = e >> 7, c = e & 127;
    g_wt[p][s][d][c] = lt[d * 132 + c];
  }
}

// --- main: fused window block, 1024 threads (16 waves -> 4 waves/SIMD) -------
// P1/P3 wave roles: s1 = w>>3 (half), jl = 32*((w>>1)&3), mh = w&1 (row half).
// P2 wave roles: wm = w&3 (16-row group), heads {2*(w>>2), +1}.
// Scores computed SWAPPED (S^T = K·Q^T) so each lane owns one q-row of P;
// PV A-frag assembled in-register via shfl transpose (no pl LDS scratch).
__global__ __launch_bounds__(1024, 4) void k_main(
    const float* __restrict__ x, float* __restrict__ out,
    const float* __restrict__ qb, const float* __restrict__ kb,
    const float* __restrict__ vb, const float* __restrict__ pb) {
  __shared__ __align__(16) unsigned short xs[N_ * 264];   // x, later attn-out
  __shared__ __align__(16) unsigned short qs[N_ * 264];   // qn*scale
  __shared__ __align__(16) unsigned short ks[N_ * 264];   // kn
  __shared__ __align__(16) unsigned short vt[C_ * 72];    // v^T [chan][tok]

  const int t    = threadIdx.x;
  const int lane = t & 63;
  const int w    = __builtin_amdgcn_readfirstlane(t >> 6);  // 0..15
  const int b    = blockIdx.x;
  const int l15  = lane & 15;
  const int qd   = lane >> 4;

  // P0: stage x -> bf16 LDS
  {
    const float4* xg = (const float4*)(x + (size_t)b * (N_ * C_));
#pragma unroll
    for (int it = 0; it < 4; ++it) {
      int e = t + 1024 * it;
      int row = e >> 6, c4 = (e & 63) << 2;
      float4 v = xg[e];
      uint2 pk;
      pk.x = ((unsigned)f2b(v.y) << 16) | f2b(v.x);
      pk.y = ((unsigned)f2b(v.w) << 16) | f2b(v.z);
      *(uint2*)&xs[row * 264 + c4] = pk;
    }
  }
  __syncthreads();

  // P1: q,k,v dual-branch residual projections (+ l2norm, q-scale), MFMA
  const int s1 = w >> 3;            // half
  const int jls = (w >> 1) & 3;
  const int jl = 32 * jls;          // col base within half
  const int mh = w & 1;             // row half (rows 32*mh .. +31)
  const float scl = g_scale[s1 * 4 + jls];
  for (int pj = 0; pj < 3; ++pj) {
    const float* bi = pj == 0 ? qb : (pj == 1 ? kb : vb);
    float4v acc[2][2];
    {
      float b0 = bi[s1 * C2_ + jl + l15], b1 = bi[s1 * C2_ + jl + 16 + l15];
#pragma unroll
      for (int mt = 0; mt < 2; ++mt) {
        acc[mt][0] = float4v{b0, b0, b0, b0};
        acc[mt][1] = float4v{b1, b1, b1, b1};
      }
    }
    const unsigned short* wt = &g_wt[pj][s1][0][0];
#pragma unroll
    for (int kc = 0; kc < 4; ++kc) {
      int ko = kc * 32 + qd * 8;
      short8 a[2], bf[2];
#pragma unroll
      for (int mt = 0; mt < 2; ++mt)
        a[mt] = *(const short8*)&xs[(32 * mh + mt * 16 + l15) * 264 + s1 * 128 + ko];
      bf[0] = *(const short8*)&wt[(jl + l15) * C2_ + ko];
      bf[1] = *(const short8*)&wt[(jl + 16 + l15) * C2_ + ko];
#pragma unroll
      for (int mt = 0; mt < 2; ++mt)
#pragma unroll
        for (int nt = 0; nt < 2; ++nt)
          acc[mt][nt] = __builtin_amdgcn_mfma_f32_16x16x32_bf16(
              a[mt], bf[nt], acc[mt][nt], 0, 0, 0);
    }
    // epilogue: +residual, l2norm (q,k), write to LDS
    unsigned short* dst = pj == 0 ? qs : ks;
#pragma unroll
    for (int mt = 0; mt < 2; ++mt) {
      int row0 = 32 * mh + mt * 16 + qd * 4;
      float vv[2][4];
#pragma unroll
      for (int nt = 0; nt < 2; ++nt)
#pragma unroll
        for (int r = 0; r < 4; ++r)
          vv[nt][r] = acc[mt][nt][r] +
                      b2f(xs[(row0 + r) * 264 + s1 * 128 + jl + nt * 16 + l15]);
      if (pj < 2) {
        float ss[4];
#pragma unroll
        for (int r = 0; r < 4; ++r) ss[r] = vv[0][r] * vv[0][r] + vv[1][r] * vv[1][r];
#pragma unroll
        for (int m = 1; m < 16; m <<= 1)
#pragma unroll
          for (int r = 0; r < 4; ++r) ss[r] += __shfl_xor(ss[r], m, 64);
#pragma unroll
        for (int r = 0; r < 4; ++r) {
          float rn = 1.0f / fmaxf(sqrtf(ss[r]), 1e-12f);
          if (pj == 0) rn *= scl;
          vv[0][r] *= rn;
          vv[1][r] *= rn;
        }
#pragma unroll
        for (int nt = 0; nt < 2; ++nt)
#pragma unroll
          for (int r = 0; r < 4; ++r)
            dst[(row0 + r) * 264 + s1 * 128 + jl + nt * 16 + l15] = f2b(vv[nt][r]);
      } else {
        // v -> transposed [chan][token], packed 4-token (8B) stores
#pragma unroll
        for (int nt = 0; nt < 2; ++nt) {
          int chan = s1 * 128 + jl + nt * 16 + l15;
          uint2 pk;
          pk.x = ((unsigned)f2b(vv[nt][1]) << 16) | f2b(vv[nt][0]);
          pk.y = ((unsigned)f2b(vv[nt][3]) << 16) | f2b(vv[nt][2]);
          *(uint2*)&vt[chan * 72 + row0] = pk;
        }
      }
    }
  }
  __syncthreads();

  // P2: attention — zero barriers. Swapped scores: sacc[nt] = S^T tile,
  // D[row = k-token nt*16+qd*4+r][col = q-token 16*wm+l15].
  const int wm = w & 3, wg = w >> 2;
  const float* sbb = g_sb + (size_t)(b & 63) * (H_ * N_ * N_);
  const int hi_sel = lane & 32;                       // qd >= 2
  const int src0 = l15 | ((((qd << 1) + 0) & 3) << 4);
  const int src1 = l15 | ((((qd << 1) + 1) & 3) << 4);
#pragma unroll
  for (int hh = 0; hh < 2; ++hh) {
    const int h = 2 * wg + hh;
    const float* sbh = sbb + h * 4096;
    // B operand = Q rows of this wave's 16-row group
    short8 bq = *(const short8*)&qs[(16 * wm + l15) * 264 + h * 32 + qd * 8];
    float4v sacc[4];
#pragma unroll
    for (int nt = 0; nt < 4; ++nt) {
      // C init = bias[q = 16wm+l15][k = nt*16 + qd*4 + r], natural order -> float4
      float4 cv = *(const float4*)&sbh[(16 * wm + l15) * 64 + nt * 16 + qd * 4];
      float4v c = {cv.x, cv.y, cv.z, cv.w};
      short8 ak = *(const short8*)&ks[(nt * 16 + l15) * 264 + h * 32 + qd * 8];
      sacc[nt] = __builtin_amdgcn_mfma_f32_16x16x32_bf16(ak, bq, c, 0, 0, 0);
    }
    // softmax: lane owns q-row l15, k = nt*16 + qd*4 + r (16 of 64 entries)
    float e[4][4];
    float s = 0.f;
#pragma unroll
    for (int nt = 0; nt < 4; ++nt)
#pragma unroll
      for (int r = 0; r < 4; ++r) {
        e[nt][r] = __expf(sacc[nt][r]);
        s += e[nt][r];
      }
    s += __shfl_xor(s, 16, 64);
    s += __shfl_xor(s, 32, 64);
    float rr = 1.0f / s;
    // pack P into bf16 pairs: pk[nt][rp] = P[k=16nt+4qd+2rp], P[k+1]
    unsigned pk[4][2];
#pragma unroll
    for (int nt = 0; nt < 4; ++nt)
#pragma unroll
      for (int rp = 0; rp < 2; ++rp)
        pk[nt][rp] = ((unsigned)f2b(e[nt][2 * rp + 1] * rr) << 16) |
                     f2b(e[nt][2 * rp] * rr);
    // in-register 4x4 u32 transpose across qd groups: lane needs
    // a[kc].u[j2] = P-pair at k = 32*kc + 8*qd + 2*j2, which lives at
    // src lane (l15, sqd=(2qd + (j2>>1))&3), reg pk[2kc + (qd>>1)][j2&1].
    U8 au[2];
#pragma unroll
    for (int j2 = 0; j2 < 4; ++j2) {
      int src = (j2 >> 1) ? src1 : src0;
      int rp = j2 & 1;
      int r0 = __shfl((int)pk[0][rp], src, 64);
      int r1 = __shfl((int)pk[1][rp], src, 64);
      int r2 = __shfl((int)pk[2][rp], src, 64);
      int r3 = __shfl((int)pk[3][rp], src, 64);
      au[0].u[j2] = hi_sel ? (unsigned)r1 : (unsigned)r0;
      au[1].u[j2] = hi_sel ? (unsigned)r3 : (unsigned)r2;
    }
    // PV: O = P @ V (A in registers, B from vt, contiguous b128)
    float4v oacc[2];
    oacc[0] = float4v{0, 0, 0, 0};
    oacc[1] = float4v{0, 0, 0, 0};
#pragma unroll
    for (int kc = 0; kc < 2; ++kc) {
      short8 ap = au[kc].s;
#pragma unroll
      for (int nt2 = 0; nt2 < 2; ++nt2) {
        short8 bv = *(const short8*)&vt[(h * 32 + nt2 * 16 + l15) * 72 + kc * 32 + qd * 8];
        oacc[nt2] = __builtin_amdgcn_mfma_f32_16x16x32_bf16(ap, bv, oacc[nt2], 0, 0, 0);
      }
    }
    // O -> xs rows [16wm..), chans [32h..): wave-unique region
#pragma unroll
    for (int nt2 = 0; nt2 < 2; ++nt2)
#pragma unroll
      for (int r = 0; r < 4; ++r)
        xs[(16 * wm + qd * 4 + r) * 264 + h * 32 + nt2 * 16 + l15] = f2b(oacc[nt2][r]);
  }
  __syncthreads();

  // P3: output projection (no residual/norm), MFMA, fp32 stores
  {
    float4v acc[2][2];
    float b0 = pb[s1 * C2_ + jl + l15], b1 = pb[s1 * C2_ + jl + 16 + l15];
#pragma unroll
    for (int mt = 0; mt < 2; ++mt) {
      acc[mt][0] = float4v{b0, b0, b0, b0};
      acc[mt][1] = float4v{b1, b1, b1, b1};
    }
    const unsigned short* wt = &g_wt[3][s1][0][0];
#pragma unroll
    for (int kc = 0; kc < 4; ++kc) {
      int ko = kc * 32 + qd * 8;
      short8 a[2], bf[2];
#pragma unroll
      for (int mt = 0; mt < 2; ++mt)
        a[mt] = *(const short8*)&xs[(32 * mh + mt * 16 + l15) * 264 + s1 * 128 + ko];
      bf[0] = *(const short8*)&wt[(jl + l15) * C2_ + ko];
      bf[1] = *(const short8*)&wt[(jl + 16 + l15) * C2_ + ko];
#pragma unroll
      for (int mt = 0; mt < 2; ++mt)
#pragma unroll
        for (int nt = 0; nt < 2; ++nt)
          acc[mt][nt] = __builtin_amdgcn_mfma_f32_16x16x32_bf16(
              a[mt], bf[nt], acc[mt][nt], 0, 0, 0);
    }
#pragma unroll
    for (int mt = 0; mt < 2; ++mt)
#pragma unroll
      for (int nt = 0; nt < 2; ++nt)
#pragma unroll
        for (int r = 0; r < 4; ++r)
          out[((size_t)b * N_ + 32 * mh + mt * 16 + qd * 4 + r) * C_ +
              s1 * 128 + jl + nt * 16 + l15] = acc[mt][nt][r];
  }
}

extern "C" void kernel_launch(void* const* d_in, const int* in_sizes, int n_in,
                              void* d_out, int out_size, void* d_ws, size_t ws_size,
                              hipStream_t stream) {
  const float* x    = (const float*)d_in[0];
  const float* mask = (const float*)d_in[1];
  const float* qw   = (const float*)d_in[2];
  const float* qb   = (const float*)d_in[3];
  const float* kw   = (const float*)d_in[4];
  const float* kb   = (const float*)d_in[5];
  const float* vw   = (const float*)d_in[6];
  const float* vb   = (const float*)d_in[7];
  const float* pw   = (const float*)d_in[8];
  const float* pb   = (const float*)d_in[9];
  const float* w1   = (const float*)d_in[10];
  const float* b1   = (const float*)d_in[11];
  const float* w2   = (const float*)d_in[12];
  const float* ls   = (const float*)d_in[13];
  const float* tbl  = (const float*)d_in[14];
  const int*   rpi  = (const int*)d_in[15];
  float* out = (float*)d_out;

  k_prep1<<<1, 256, 0, stream>>>(tbl, w1, b1, w2, ls);
  k_prep2<<<2048, 256, 0, stream>>>(mask, rpi);
  k_prepw<<<8, 256, 0, stream>>>(qw, kw, vw, pw);
  k_main<<<B_, 1024, 0, stream>>>(x, out, qb, kb, vb, pb);
}

// Round 3
// 391.888 us; speedup vs baseline: 1.0744x; 1.0744x over previous
//
#include <hip/hip_runtime.h>
#include <stdint.h>

#define B_    2048
#define N_    64
#define C_    256
#define C2_   128
#define H_    8
#define NW_   64
#define NPOS  225   // 15*15
#define PX    136   // xs/qs/ks row stride in shorts (128 + 8 pad, 16B-aligned rows)
#define PV    72    // vt row stride in shorts

typedef __attribute__((ext_vector_type(8))) short short8;
typedef __attribute__((ext_vector_type(4))) float float4v;

union U8 { unsigned u[4]; short8 s; };

// Module-scope scratch (graph-safe; rewritten by prep kernels every launch).
__device__ float g_scale[H_];                    // exp(min(logit_scale, log100))
__device__ float g_t8[NPOS][H_];                 // CPB-MLP table
__device__ __align__(16) float g_sb[NW_ * H_ * N_ * N_];  // NATURAL [w][h][q row][k col]
__device__ unsigned short g_wt[4][2][C2_][C2_];  // bf16 W^T: [proj][half][d][c]

__device__ __forceinline__ float b2f(unsigned short u) {
  return __uint_as_float(((unsigned int)u) << 16);
}
__device__ __forceinline__ unsigned short f2b(float f) {
  unsigned int u = __float_as_uint(f);
  u += 0x7fffu + ((u >> 16) & 1u);    // RNE
  return (unsigned short)(u >> 16);
}

// --- prep 1: CPB-MLP table + per-head scale (1 block, LDS-staged weights) ----
__global__ __launch_bounds__(256) void k_prep1(
    const float* __restrict__ tbl, const float* __restrict__ w1,
    const float* __restrict__ b1, const float* __restrict__ w2,
    const float* __restrict__ ls) {
  __shared__ float sw1[256], sb1[128], sw2[1024];
  const int t = threadIdx.x;
  sw1[t] = w1[t];
  if (t < 128) sb1[t] = b1[t];
#pragma unroll
  for (int it = 0; it < 4; ++it) sw2[it * 256 + t] = w2[it * 256 + t];
  __syncthreads();
  if (t < NPOS) {
    float a0 = tbl[2 * t], a1 = tbl[2 * t + 1];
    float acc[H_];
#pragma unroll
    for (int h = 0; h < H_; ++h) acc[h] = 0.f;
    for (int j = 0; j < 128; ++j) {
      float hid = fmaxf(a0 * sw1[j] + a1 * sw1[128 + j] + sb1[j], 0.f);
#pragma unroll
      for (int h = 0; h < H_; ++h) acc[h] += hid * sw2[j * H_ + h];
    }
#pragma unroll
    for (int h = 0; h < H_; ++h) g_t8[t][h] = acc[h];
  }
  if (t < H_) g_scale[t] = __expf(fminf(ls[t], 4.6051702f));
}

// --- prep 2: 16*sigmoid(bias)+mask, NATURAL order [w][h][q][k] ---------------
__global__ __launch_bounds__(256) void k_prep2(
    const float* __restrict__ mask, const int* __restrict__ rpi) {
  const int base = blockIdx.x * 1024;
#pragma unroll
  for (int it = 0; it < 4; ++it) {
    int idx = base + it * 256 + threadIdx.x;     // [0, 2M)
    int j  = idx & 63;            // col (k) — fastest => coalesced reads/writes
    int i  = (idx >> 6) & 63;     // row (q)
    int h  = (idx >> 12) & 7;
    int wd = idx >> 15;
    float v = g_t8[rpi[i * 64 + j]][h];
    g_sb[idx] = 16.f / (1.f + __expf(-v)) + mask[wd * 4096 + i * 64 + j];
  }
}

// --- prep 3: weights -> bf16 transposed via LDS (coalesced both sides) -------
__global__ __launch_bounds__(256) void k_prepw(
    const float* __restrict__ qw, const float* __restrict__ kw,
    const float* __restrict__ vw, const float* __restrict__ pw) {
  __shared__ unsigned short lt[128 * 132];
  const int t = threadIdx.x;
  const int p = blockIdx.x >> 1, s = blockIdx.x & 1;
  const float* src = (p == 0 ? qw : p == 1 ? kw : p == 2 ? vw : pw) + s * (C2_ * C2_);
#pragma unroll
  for (int it = 0; it < 64; ++it) {
    int e = it * 256 + t;         // e = c*128 + d, coalesced read
    int c = e >> 7, d = e & 127;
    lt[d * 132 + c] = f2b(src[e]);
  }
  __syncthreads();
#pragma unroll
  for (int it = 0; it < 64; ++it) {
    int e = it * 256 + t;         // e = d*128 + c, coalesced write
    int d = e >> 7, c = e & 127;
    g_wt[p][s][d][c] = lt[d * 132 + c];
  }
}

// --- main: HALF-window block (64 tok x 128 chan, 4 heads), 512 thr, 8 waves --
// Channel halves never interact (block-diagonal projections, heads 0-3 in half
// 0, 4-7 in half 1), so each window = 2 independent blocks -> LDS 70.7 KB ->
// 2 blocks/CU: independent barrier domains overlap HBM and compute phases.
// P1/P3 wave roles: jl = 32*(w>>1) col slice, mh = w&1 row half.
// P2 wave roles: local head hl = w>>1, row half rh = w&1 (two 16-row groups).
// Scores SWAPPED (S^T = K.Q^T) so each lane owns one q-row of P; PV A-frag
// assembled in-register via shfl transpose (no P scratch in LDS).
__global__ __launch_bounds__(512) void k_main(
    const float* __restrict__ x, float* __restrict__ out,
    const float* __restrict__ qb, const float* __restrict__ kb,
    const float* __restrict__ vb, const float* __restrict__ pb) {
  __shared__ __align__(16) unsigned short xs[N_ * PX];   // x half, later attn-out
  __shared__ __align__(16) unsigned short qs[N_ * PX];   // qn*scale
  __shared__ __align__(16) unsigned short ks[N_ * PX];   // kn
  __shared__ __align__(16) unsigned short vt[C2_ * PV];  // v^T [chan][tok]

  const int t    = threadIdx.x;
  const int lane = t & 63;
  const int w    = __builtin_amdgcn_readfirstlane(t >> 6);  // 0..7
  const int bs   = blockIdx.x;
  const int b    = bs >> 1;          // window-batch
  const int s1   = bs & 1;           // channel half
  const int l15  = lane & 15;
  const int qd   = lane >> 4;

  // P0: stage x half -> bf16 LDS
  {
    const float* xg = x + (size_t)b * (N_ * C_) + s1 * C2_;
#pragma unroll
    for (int it = 0; it < 4; ++it) {
      int e = t + 512 * it;          // 0..2047 = 64 rows x 32 float4
      int row = e >> 5, c4 = (e & 31) << 2;
      float4 v = *(const float4*)&xg[row * C_ + c4];
      uint2 pk;
      pk.x = ((unsigned)f2b(v.y) << 16) | f2b(v.x);
      pk.y = ((unsigned)f2b(v.w) << 16) | f2b(v.z);
      *(uint2*)&xs[row * PX + c4] = pk;
    }
  }
  __syncthreads();

  // P1: q,k,v dual-branch residual projections (+ l2norm, q-scale), MFMA
  const int jls = w >> 1;
  const int jl  = 32 * jls;          // col base within half
  const int mh  = w & 1;             // row half (rows 32*mh .. +31)
  const float scl = g_scale[s1 * 4 + jls];
  for (int pj = 0; pj < 3; ++pj) {
    const float* bi = pj == 0 ? qb : (pj == 1 ? kb : vb);
    float4v acc[2][2];
    {
      float b0 = bi[s1 * C2_ + jl + l15], b1 = bi[s1 * C2_ + jl + 16 + l15];
#pragma unroll
      for (int mt = 0; mt < 2; ++mt) {
        acc[mt][0] = float4v{b0, b0, b0, b0};
        acc[mt][1] = float4v{b1, b1, b1, b1};
      }
    }
    const unsigned short* wt = &g_wt[pj][s1][0][0];
#pragma unroll
    for (int kc = 0; kc < 4; ++kc) {
      int ko = kc * 32 + qd * 8;
      short8 a[2], bf[2];
#pragma unroll
      for (int mt = 0; mt < 2; ++mt)
        a[mt] = *(const short8*)&xs[(32 * mh + mt * 16 + l15) * PX + ko];
      bf[0] = *(const short8*)&wt[(jl + l15) * C2_ + ko];
      bf[1] = *(const short8*)&wt[(jl + 16 + l15) * C2_ + ko];
#pragma unroll
      for (int mt = 0; mt < 2; ++mt)
#pragma unroll
        for (int nt = 0; nt < 2; ++nt)
          acc[mt][nt] = __builtin_amdgcn_mfma_f32_16x16x32_bf16(
              a[mt], bf[nt], acc[mt][nt], 0, 0, 0);
    }
    // epilogue: +residual, l2norm (q,k), write to LDS
    unsigned short* dst = pj == 0 ? qs : ks;
#pragma unroll
    for (int mt = 0; mt < 2; ++mt) {
      int row0 = 32 * mh + mt * 16 + qd * 4;
      float vv[2][4];
#pragma unroll
      for (int nt = 0; nt < 2; ++nt)
#pragma unroll
        for (int r = 0; r < 4; ++r)
          vv[nt][r] = acc[mt][nt][r] +
                      b2f(xs[(row0 + r) * PX + jl + nt * 16 + l15]);
      if (pj < 2) {
        float ss[4];
#pragma unroll
        for (int r = 0; r < 4; ++r) ss[r] = vv[0][r] * vv[0][r] + vv[1][r] * vv[1][r];
#pragma unroll
        for (int m = 1; m < 16; m <<= 1)
#pragma unroll
          for (int r = 0; r < 4; ++r) ss[r] += __shfl_xor(ss[r], m, 64);
#pragma unroll
        for (int r = 0; r < 4; ++r) {
          float rn = 1.0f / fmaxf(sqrtf(ss[r]), 1e-12f);
          if (pj == 0) rn *= scl;
          vv[0][r] *= rn;
          vv[1][r] *= rn;
        }
#pragma unroll
        for (int nt = 0; nt < 2; ++nt)
#pragma unroll
          for (int r = 0; r < 4; ++r)
            dst[(row0 + r) * PX + jl + nt * 16 + l15] = f2b(vv[nt][r]);
      } else {
        // v -> transposed [chan][token], packed 4-token (8B) stores
#pragma unroll
        for (int nt = 0; nt < 2; ++nt) {
          int chan = jl + nt * 16 + l15;             // local chan 0..127
          uint2 pk;
          pk.x = ((unsigned)f2b(vv[nt][1]) << 16) | f2b(vv[nt][0]);
          pk.y = ((unsigned)f2b(vv[nt][3]) << 16) | f2b(vv[nt][2]);
          *(uint2*)&vt[chan * PV + row0] = pk;
        }
      }
    }
  }
  __syncthreads();

  // P2: attention — zero barriers. Swapped scores: sacc[nt] = S^T tile,
  // D[row = k-token nt*16+qd*4+r][col = q-token r0+l15].
  const int hl = w >> 1;             // local head 0..3
  const int rh = w & 1;              // row half
  const int h  = s1 * 4 + hl;        // global head
  const float* sbh = g_sb + ((size_t)(b & 63) * H_ + h) * 4096;
  const int hi_sel = lane & 32;      // qd >= 2
  const int src0 = l15 | ((((qd << 1) + 0) & 3) << 4);
  const int src1 = l15 | ((((qd << 1) + 1) & 3) << 4);
#pragma unroll
  for (int mq = 0; mq < 2; ++mq) {
    const int r0 = 32 * rh + 16 * mq;
    // B operand = Q rows [r0, r0+16)
    short8 bq = *(const short8*)&qs[(r0 + l15) * PX + hl * 32 + qd * 8];
    float4v sacc[4];
#pragma unroll
    for (int nt = 0; nt < 4; ++nt) {
      // C init = bias[q = r0+l15][k = nt*16 + qd*4 + r], natural order -> float4
      float4 cv = *(const float4*)&sbh[(r0 + l15) * 64 + nt * 16 + qd * 4];
      float4v c = {cv.x, cv.y, cv.z, cv.w};
      short8 ak = *(const short8*)&ks[(nt * 16 + l15) * PX + hl * 32 + qd * 8];
      sacc[nt] = __builtin_amdgcn_mfma_f32_16x16x32_bf16(ak, bq, c, 0, 0, 0);
    }
    // softmax: lane owns q-row r0+l15, k = nt*16 + qd*4 + r (16 of 64 entries)
    float e[4][4];
    float s = 0.f;
#pragma unroll
    for (int nt = 0; nt < 4; ++nt)
#pragma unroll
      for (int r = 0; r < 4; ++r) {
        e[nt][r] = __expf(sacc[nt][r]);
        s += e[nt][r];
      }
    s += __shfl_xor(s, 16, 64);
    s += __shfl_xor(s, 32, 64);
    float rr = 1.0f / s;
    // pack P into bf16 pairs: pk[nt][rp] = P[k=16nt+4qd+2rp], P[k+1]
    unsigned pk[4][2];
#pragma unroll
    for (int nt = 0; nt < 4; ++nt)
#pragma unroll
      for (int rp = 0; rp < 2; ++rp)
        pk[nt][rp] = ((unsigned)f2b(e[nt][2 * rp + 1] * rr) << 16) |
                     f2b(e[nt][2 * rp] * rr);
    // in-register 4x4 u32 transpose across qd groups: lane needs
    // a[kc].u[j2] = P-pair at k = 32*kc + 8*qd + 2*j2, which lives at
    // src lane (l15, sqd=(2qd + (j2>>1))&3), reg pk[2kc + (qd>>1)][j2&1].
    U8 au[2];
#pragma unroll
    for (int j2 = 0; j2 < 4; ++j2) {
      int src = (j2 >> 1) ? src1 : src0;
      int rp = j2 & 1;
      int r0v = __shfl((int)pk[0][rp], src, 64);
      int r1v = __shfl((int)pk[1][rp], src, 64);
      int r2v = __shfl((int)pk[2][rp], src, 64);
      int r3v = __shfl((int)pk[3][rp], src, 64);
      au[0].u[j2] = hi_sel ? (unsigned)r1v : (unsigned)r0v;
      au[1].u[j2] = hi_sel ? (unsigned)r3v : (unsigned)r2v;
    }
    // PV: O = P @ V (A in registers, B from vt, contiguous b128)
    float4v oacc[2];
    oacc[0] = float4v{0, 0, 0, 0};
    oacc[1] = float4v{0, 0, 0, 0};
#pragma unroll
    for (int kc = 0; kc < 2; ++kc) {
      short8 ap = au[kc].s;
#pragma unroll
      for (int nt2 = 0; nt2 < 2; ++nt2) {
        short8 bv = *(const short8*)&vt[(hl * 32 + nt2 * 16 + l15) * PV + kc * 32 + qd * 8];
        oacc[nt2] = __builtin_amdgcn_mfma_f32_16x16x32_bf16(ap, bv, oacc[nt2], 0, 0, 0);
      }
    }
    // O -> xs rows [r0..r0+16), chans [32hl..): wave-unique region
#pragma unroll
    for (int nt2 = 0; nt2 < 2; ++nt2)
#pragma unroll
      for (int r = 0; r < 4; ++r)
        xs[(r0 + qd * 4 + r) * PX + hl * 32 + nt2 * 16 + l15] = f2b(oacc[nt2][r]);
  }
  __syncthreads();

  // P3: output projection (no residual/norm), MFMA, fp32 stores
  {
    float4v acc[2][2];
    float b0 = pb[s1 * C2_ + jl + l15], b1 = pb[s1 * C2_ + jl + 16 + l15];
#pragma unroll
    for (int mt = 0; mt < 2; ++mt) {
      acc[mt][0] = float4v{b0, b0, b0, b0};
      acc[mt][1] = float4v{b1, b1, b1, b1};
    }
    const unsigned short* wt = &g_wt[3][s1][0][0];
#pragma unroll
    for (int kc = 0; kc < 4; ++kc) {
      int ko = kc * 32 + qd * 8;
      short8 a[2], bf[2];
#pragma unroll
      for (int mt = 0; mt < 2; ++mt)
        a[mt] = *(const short8*)&xs[(32 * mh + mt * 16 + l15) * PX + ko];
      bf[0] = *(const short8*)&wt[(jl + l15) * C2_ + ko];
      bf[1] = *(const short8*)&wt[(jl + 16 + l15) * C2_ + ko];
#pragma unroll
      for (int mt = 0; mt < 2; ++mt)
#pragma unroll
        for (int nt = 0; nt < 2; ++nt)
          acc[mt][nt] = __builtin_amdgcn_mfma_f32_16x16x32_bf16(
              a[mt], bf[nt], acc[mt][nt], 0, 0, 0);
    }
#pragma unroll
    for (int mt = 0; mt < 2; ++mt)
#pragma unroll
      for (int nt = 0; nt < 2; ++nt)
#pragma unroll
        for (int r = 0; r < 4; ++r)
          out[((size_t)b * N_ + 32 * mh + mt * 16 + qd * 4 + r) * C_ +
              s1 * C2_ + jl + nt * 16 + l15] = acc[mt][nt][r];
  }
}

extern "C" void kernel_launch(void* const* d_in, const int* in_sizes, int n_in,
                              void* d_out, int out_size, void* d_ws, size_t ws_size,
                              hipStream_t stream) {
  const float* x    = (const float*)d_in[0];
  const float* mask = (const float*)d_in[1];
  const float* qw   = (const float*)d_in[2];
  const float* qb   = (const float*)d_in[3];
  const float* kw   = (const float*)d_in[4];
  const float* kb   = (const float*)d_in[5];
  const float* vw   = (const float*)d_in[6];
  const float* vb   = (const float*)d_in[7];
  const float* pw   = (const float*)d_in[8];
  const float* pb   = (const float*)d_in[9];
  const float* w1   = (const float*)d_in[10];
  const float* b1   = (const float*)d_in[11];
  const float* w2   = (const float*)d_in[12];
  const float* ls   = (const float*)d_in[13];
  const float* tbl  = (const float*)d_in[14];
  const int*   rpi  = (const int*)d_in[15];
  float* out = (float*)d_out;

  k_prep1<<<1, 256, 0, stream>>>(tbl, w1, b1, w2, ls);
  k_prep2<<<2048, 256, 0, stream>>>(mask, rpi);
  k_prepw<<<8, 256, 0, stream>>>(qw, kw, vw, pw);
  k_main<<<B_ * 2, 512, 0, stream>>>(x, out, qb, kb, vb, pb);
}

// Round 5
// 384.549 us; speedup vs baseline: 1.0949x; 1.0191x over previous
//
#include <hip/hip_runtime.h>
#include <hip/hip_bf16.h>
#include <stdint.h>

#define B_    2048
#define N_    64
#define C_    256
#define C2_   128
#define H_    8
#define NW_   64
#define NPOS  225   // 15*15
#define PX    136   // xs/qs/ks row stride in shorts (128 + 8 pad, 16B-aligned rows)
#define PV    72    // vt row stride in shorts

typedef __attribute__((ext_vector_type(8))) short short8;
typedef __attribute__((ext_vector_type(4))) float float4v;

union U8 { unsigned u[4]; short8 s; };

// Module-scope scratch (graph-safe; rewritten by prep kernels every launch).
__device__ float g_scale[H_];                    // exp(min(logit_scale, log100))
__device__ float g_t8[NPOS][H_];                 // CPB-MLP table
__device__ __align__(16) float g_sb[NW_ * H_ * N_ * N_];  // NATURAL [w][h][q row][k col]
__device__ unsigned short g_wt[4][2][C2_][C2_];  // bf16 (I+W)^T for q/k/v, W^T for p

__device__ __forceinline__ float b2f(unsigned short u) {
  return __uint_as_float(((unsigned int)u) << 16);
}
__device__ __forceinline__ unsigned short f2b(float f) {
  unsigned int u = __float_as_uint(f);
  u += 0x7fffu + ((u >> 16) & 1u);    // RNE
  return (unsigned short)(u >> 16);
}
// packed RNE f32x2 -> bf16x2 (low = lo); compiler can emit v_cvt_pk_bf16_f32
__device__ __forceinline__ unsigned f2b2(float lo, float hi) {
  __hip_bfloat162 h = __float22bfloat162_rn(float2{lo, hi});
  unsigned u;
  __builtin_memcpy(&u, &h, 4);
  return u;
}
// sum over each 16-lane row via DPP (VALU pipe, not LDS pipe)
__device__ __forceinline__ float rowsum16(float v) {
  int x = __float_as_int(v);
  v += __int_as_float(__builtin_amdgcn_update_dpp(0, x, 0xB1, 0xF, 0xF, false));  // quad_perm [1,0,3,2]
  x = __float_as_int(v);
  v += __int_as_float(__builtin_amdgcn_update_dpp(0, x, 0x4E, 0xF, 0xF, false));  // quad_perm [2,3,0,1]
  x = __float_as_int(v);
  v += __int_as_float(__builtin_amdgcn_update_dpp(0, x, 0x124, 0xF, 0xF, false)); // row_ror:4
  x = __float_as_int(v);
  v += __int_as_float(__builtin_amdgcn_update_dpp(0, x, 0x128, 0xF, 0xF, false)); // row_ror:8
  return v;
}

// --- prep A: fused {weights->bf16^T (+identity fold), CPB-MLP table, scale} --
// blocks 0..7: one (proj, half) weight transpose each; block 8: CPB-MLP.
__global__ __launch_bounds__(256) void k_prep_a(
    const float* __restrict__ qw, const float* __restrict__ kw,
    const float* __restrict__ vw, const float* __restrict__ pw,
    const float* __restrict__ tbl, const float* __restrict__ w1,
    const float* __restrict__ b1, const float* __restrict__ w2,
    const float* __restrict__ ls) {
  __shared__ unsigned short lt[128 * 132];
  const int t = threadIdx.x;
  if (blockIdx.x < 8) {
    const int p = blockIdx.x >> 1, s = blockIdx.x & 1;
    const float* src = (p == 0 ? qw : p == 1 ? kw : p == 2 ? vw : pw) + s * (C2_ * C2_);
#pragma unroll
    for (int it = 0; it < 64; ++it) {
      int e = it * 256 + t;         // e = c*128 + d, coalesced read
      int c = e >> 7, d = e & 127;
      lt[d * 132 + c] = f2b(src[e]);
    }
    __syncthreads();
#pragma unroll
    for (int it = 0; it < 64; ++it) {
      int e = it * 256 + t;         // e = d*128 + c, coalesced write
      int d = e >> 7, c = e & 127;
      unsigned short u = lt[d * 132 + c];
      if (p < 3 && d == c) u = f2b(b2f(u) + 1.0f);   // residual fold: I + W
      g_wt[p][s][d][c] = u;
    }
  } else {
    float* fsh = (float*)lt;         // alias: sw1[256] | sb1[128] | sw2[1024]
    float* sw1 = fsh;
    float* sb1 = fsh + 256;
    float* sw2 = fsh + 384;
    sw1[t] = w1[t];
    if (t < 128) sb1[t] = b1[t];
#pragma unroll
    for (int it = 0; it < 4; ++it) sw2[it * 256 + t] = w2[it * 256 + t];
    __syncthreads();
    if (t < NPOS) {
      float a0 = tbl[2 * t], a1 = tbl[2 * t + 1];
      float acc[H_];
#pragma unroll
      for (int h = 0; h < H_; ++h) acc[h] = 0.f;
      for (int j = 0; j < 128; ++j) {
        float hid = fmaxf(a0 * sw1[j] + a1 * sw1[128 + j] + sb1[j], 0.f);
#pragma unroll
        for (int h = 0; h < H_; ++h) acc[h] += hid * sw2[j * H_ + h];
      }
#pragma unroll
      for (int h = 0; h < H_; ++h) g_t8[t][h] = acc[h];
    }
    if (t < H_) g_scale[t] = __expf(fminf(ls[t], 4.6051702f));
  }
}

// --- prep 2: 16*sigmoid(bias)+mask, NATURAL order [w][h][q][k] ---------------
__global__ __launch_bounds__(256) void k_prep2(
    const float* __restrict__ mask, const int* __restrict__ rpi) {
  const int base = blockIdx.x * 1024;
#pragma unroll
  for (int it = 0; it < 4; ++it) {
    int idx = base + it * 256 + threadIdx.x;     // [0, 2M)
    int j  = idx & 63;            // col (k) — fastest => coalesced reads/writes
    int i  = (idx >> 6) & 63;     // row (q)
    int h  = (idx >> 12) & 7;
    int wd = idx >> 15;
    float v = g_t8[rpi[i * 64 + j]][h];
    g_sb[idx] = 16.f / (1.f + __expf(-v)) + mask[wd * 4096 + i * 64 + j];
  }
}

// --- main: HALF-window block (64 tok x 128 chan, 4 heads), 512 thr, 8 waves --
// 2 blocks/CU (LDS 70.7 KB). Residual folded into weights (no LDS residual
// reads); A-fragments hoisted across the 3 projections; K/V fragments hoisted
// across both mq; l2norm reduce on DPP (VALU pipe); packed bf16 converts;
// P2 bias prefetched before the barrier; XCD swizzle groups same-(b&7) blocks
// so g_sb slabs stay L2-resident per XCD.
__global__ __launch_bounds__(512, 4) void k_main(
    const float* __restrict__ x, float* __restrict__ out,
    const float* __restrict__ qb, const float* __restrict__ kb,
    const float* __restrict__ vb, const float* __restrict__ pb) {
  __shared__ __align__(16) unsigned short xs[N_ * PX];   // x half, later attn-out
  __shared__ __align__(16) unsigned short qs[N_ * PX];   // qn*scale
  __shared__ __align__(16) unsigned short ks[N_ * PX];   // kn
  __shared__ __align__(16) unsigned short vt[C2_ * PV];  // v^T [chan][tok]

  const int t    = threadIdx.x;
  const int lane = t & 63;
  const int w    = __builtin_amdgcn_readfirstlane(t >> 6);  // 0..7
  const int bi   = blockIdx.x;
  const int b    = ((bi >> 4) << 3) | (bi & 7);  // window-batch (XCD = bi&7 = b&7)
  const int s1   = (bi >> 3) & 1;                // channel half
  const int l15  = lane & 15;
  const int qd   = lane >> 4;

  const int jls = w >> 1;
  const int jl  = 32 * jls;          // col base within half
  const int mh  = w & 1;             // row half (rows 32*mh .. +31)
  // hoisted bias loads (latency hidden under P0)
  const int cb = s1 * C2_ + jl + l15;
  const float qb0 = qb[cb], qb1 = qb[cb + 16];
  const float kb0 = kb[cb], kb1 = kb[cb + 16];
  const float vb0 = vb[cb], vb1 = vb[cb + 16];
  const float pb0 = pb[cb], pb1 = pb[cb + 16];
  const float scl = g_scale[s1 * 4 + jls];

  // P0: stage x half -> bf16 LDS
  {
    const float* xg = x + (size_t)b * (N_ * C_) + s1 * C2_;
#pragma unroll
    for (int it = 0; it < 4; ++it) {
      int e = t + 512 * it;          // 0..2047 = 64 rows x 32 float4
      int row = e >> 5, c4 = (e & 31) << 2;
      float4 v = *(const float4*)&xg[row * C_ + c4];
      uint2 pk;
      pk.x = f2b2(v.x, v.y);
      pk.y = f2b2(v.z, v.w);
      *(uint2*)&xs[row * PX + c4] = pk;
    }
  }
  __syncthreads();

  // P1: q,k,v projections via folded weights: y = x*(I+W) + b, MFMA
  // A-fragments shared by all 3 projections -> load once.
  short8 a_all[4][2];
#pragma unroll
  for (int kc = 0; kc < 4; ++kc) {
    int ko = kc * 32 + qd * 8;
#pragma unroll
    for (int mt = 0; mt < 2; ++mt)
      a_all[kc][mt] = *(const short8*)&xs[(32 * mh + mt * 16 + l15) * PX + ko];
  }
  for (int pj = 0; pj < 3; ++pj) {
    const float bi0 = pj == 0 ? qb0 : (pj == 1 ? kb0 : vb0);
    const float bi1 = pj == 0 ? qb1 : (pj == 1 ? kb1 : vb1);
    float4v acc[2][2];
#pragma unroll
    for (int mt = 0; mt < 2; ++mt) {
      acc[mt][0] = float4v{bi0, bi0, bi0, bi0};
      acc[mt][1] = float4v{bi1, bi1, bi1, bi1};
    }
    const unsigned short* wt = &g_wt[pj][s1][0][0];
#pragma unroll
    for (int kc = 0; kc < 4; ++kc) {
      int ko = kc * 32 + qd * 8;
      short8 bf[2];
      bf[0] = *(const short8*)&wt[(jl + l15) * C2_ + ko];
      bf[1] = *(const short8*)&wt[(jl + 16 + l15) * C2_ + ko];
#pragma unroll
      for (int mt = 0; mt < 2; ++mt)
#pragma unroll
        for (int nt = 0; nt < 2; ++nt)
          acc[mt][nt] = __builtin_amdgcn_mfma_f32_16x16x32_bf16(
              a_all[kc][mt], bf[nt], acc[mt][nt], 0, 0, 0);
    }
    // epilogue: l2norm (q,k) via DPP rowsum, write to LDS
    unsigned short* dst = pj == 0 ? qs : ks;
#pragma unroll
    for (int mt = 0; mt < 2; ++mt) {
      int row0 = 32 * mh + mt * 16 + qd * 4;
      if (pj < 2) {
        float rn[4];
#pragma unroll
        for (int r = 0; r < 4; ++r) {
          float ss = acc[mt][0][r] * acc[mt][0][r] + acc[mt][1][r] * acc[mt][1][r];
          ss = rowsum16(ss);
          rn[r] = 1.0f / fmaxf(sqrtf(ss), 1e-12f);
          if (pj == 0) rn[r] *= scl;
        }
#pragma unroll
        for (int nt = 0; nt < 2; ++nt)
#pragma unroll
          for (int r = 0; r < 4; ++r)
            dst[(row0 + r) * PX + jl + nt * 16 + l15] = f2b(acc[mt][nt][r] * rn[r]);
      } else {
        // v -> transposed [chan][token], packed 4-token (8B) stores
#pragma unroll
        for (int nt = 0; nt < 2; ++nt) {
          int chan = jl + nt * 16 + l15;             // local chan 0..127
          uint2 pk;
          pk.x = f2b2(acc[mt][nt][0], acc[mt][nt][1]);
          pk.y = f2b2(acc[mt][nt][2], acc[mt][nt][3]);
          *(uint2*)&vt[chan * PV + row0] = pk;
        }
      }
    }
  }

  // P2 bias prefetch: global loads issued BEFORE the barrier (latency cover)
  const int hl = w >> 1;             // local head 0..3
  const int rh = w & 1;              // row half
  const int h  = s1 * 4 + hl;        // global head
  const float* sbh = g_sb + ((size_t)(b & 63) * H_ + h) * 4096;
  float4 cv[2][4];
#pragma unroll
  for (int mq = 0; mq < 2; ++mq)
#pragma unroll
    for (int nt = 0; nt < 4; ++nt)
      cv[mq][nt] = *(const float4*)&sbh[(32 * rh + 16 * mq + l15) * 64 + nt * 16 + qd * 4];
  __syncthreads();

  // P2: attention — zero barriers. Swapped scores: sacc[nt] = S^T tile,
  // D[row = k-token nt*16+qd*4+r][col = q-token r0+l15].
  const int hi_sel = lane & 32;      // qd >= 2
  const int src0 = l15 | ((((qd << 1) + 0) & 3) << 4);
  const int src1 = l15 | ((((qd << 1) + 1) & 3) << 4);
  // K and V fragments shared by both mq iterations -> load once.
  short8 ak[4], bv[2][2];
#pragma unroll
  for (int nt = 0; nt < 4; ++nt)
    ak[nt] = *(const short8*)&ks[(nt * 16 + l15) * PX + hl * 32 + qd * 8];
#pragma unroll
  for (int kc = 0; kc < 2; ++kc)
#pragma unroll
    for (int nt2 = 0; nt2 < 2; ++nt2)
      bv[kc][nt2] = *(const short8*)&vt[(hl * 32 + nt2 * 16 + l15) * PV + kc * 32 + qd * 8];
#pragma unroll
  for (int mq = 0; mq < 2; ++mq) {
    const int r0 = 32 * rh + 16 * mq;
    // B operand = Q rows [r0, r0+16)
    short8 bq = *(const short8*)&qs[(r0 + l15) * PX + hl * 32 + qd * 8];
    float4v sacc[4];
#pragma unroll
    for (int nt = 0; nt < 4; ++nt) {
      float4v c = {cv[mq][nt].x, cv[mq][nt].y, cv[mq][nt].z, cv[mq][nt].w};
      sacc[nt] = __builtin_amdgcn_mfma_f32_16x16x32_bf16(ak[nt], bq, c, 0, 0, 0);
    }
    // softmax: lane owns q-row r0+l15, k = nt*16 + qd*4 + r (16 of 64 entries)
    float e[4][4];
    float s = 0.f;
#pragma unroll
    for (int nt = 0; nt < 4; ++nt)
#pragma unroll
      for (int r = 0; r < 4; ++r) {
        e[nt][r] = __expf(sacc[nt][r]);
        s += e[nt][r];
      }
    s += __shfl_xor(s, 16, 64);
    s += __shfl_xor(s, 32, 64);
    float rr = 1.0f / s;
    // pack P into bf16 pairs: pk[nt][rp] = P[k=16nt+4qd+2rp], P[k+1]
    unsigned pk[4][2];
#pragma unroll
    for (int nt = 0; nt < 4; ++nt)
#pragma unroll
      for (int rp = 0; rp < 2; ++rp)
        pk[nt][rp] = f2b2(e[nt][2 * rp] * rr, e[nt][2 * rp + 1] * rr);
    // in-register 4x4 u32 transpose across qd groups: lane needs
    // a[kc].u[j2] = P-pair at k = 32*kc + 8*qd + 2*j2, which lives at
    // src lane (l15, sqd=(2qd + (j2>>1))&3), reg pk[2kc + (qd>>1)][j2&1].
    U8 au[2];
#pragma unroll
    for (int j2 = 0; j2 < 4; ++j2) {
      int src = (j2 >> 1) ? src1 : src0;
      int rp = j2 & 1;
      int r0v = __shfl((int)pk[0][rp], src, 64);
      int r1v = __shfl((int)pk[1][rp], src, 64);
      int r2v = __shfl((int)pk[2][rp], src, 64);
      int r3v = __shfl((int)pk[3][rp], src, 64);
      au[0].u[j2] = hi_sel ? (unsigned)r1v : (unsigned)r0v;
      au[1].u[j2] = hi_sel ? (unsigned)r3v : (unsigned)r2v;
    }
    // PV: O = P @ V (A in registers, B hoisted)
    float4v oacc[2];
    oacc[0] = float4v{0, 0, 0, 0};
    oacc[1] = float4v{0, 0, 0, 0};
#pragma unroll
    for (int kc = 0; kc < 2; ++kc) {
      short8 ap = au[kc].s;
#pragma unroll
      for (int nt2 = 0; nt2 < 2; ++nt2)
        oacc[nt2] = __builtin_amdgcn_mfma_f32_16x16x32_bf16(ap, bv[kc][nt2], oacc[nt2], 0, 0, 0);
    }
    // O -> xs rows [r0..r0+16), chans [32hl..): wave-unique region
#pragma unroll
    for (int nt2 = 0; nt2 < 2; ++nt2)
#pragma unroll
      for (int r = 0; r < 4; ++r)
        xs[(r0 + qd * 4 + r) * PX + hl * 32 + nt2 * 16 + l15] = f2b(oacc[nt2][r]);
  }
  __syncthreads();

  // P3: output projection (no residual/norm), MFMA, fp32 stores
  {
    float4v acc[2][2];
#pragma unroll
    for (int mt = 0; mt < 2; ++mt) {
      acc[mt][0] = float4v{pb0, pb0, pb0, pb0};
      acc[mt][1] = float4v{pb1, pb1, pb1, pb1};
    }
    const unsigned short* wt = &g_wt[3][s1][0][0];
#pragma unroll
    for (int kc = 0; kc < 4; ++kc) {
      int ko = kc * 32 + qd * 8;
      short8 a[2], bf[2];
#pragma unroll
      for (int mt = 0; mt < 2; ++mt)
        a[mt] = *(const short8*)&xs[(32 * mh + mt * 16 + l15) * PX + ko];
      bf[0] = *(const short8*)&wt[(jl + l15) * C2_ + ko];
      bf[1] = *(const short8*)&wt[(jl + 16 + l15) * C2_ + ko];
#pragma unroll
      for (int mt = 0; mt < 2; ++mt)
#pragma unroll
        for (int nt = 0; nt < 2; ++nt)
          acc[mt][nt] = __builtin_amdgcn_mfma_f32_16x16x32_bf16(
              a[mt], bf[nt], acc[mt][nt], 0, 0, 0);
    }
#pragma unroll
    for (int mt = 0; mt < 2; ++mt)
#pragma unroll
      for (int nt = 0; nt < 2; ++nt)
#pragma unroll
        for (int r = 0; r < 4; ++r)
          out[((size_t)b * N_ + 32 * mh + mt * 16 + qd * 4 + r) * C_ +
              s1 * C2_ + jl + nt * 16 + l15] = acc[mt][nt][r];
  }
}

extern "C" void kernel_launch(void* const* d_in, const int* in_sizes, int n_in,
                              void* d_out, int out_size, void* d_ws, size_t ws_size,
                              hipStream_t stream) {
  const float* x    = (const float*)d_in[0];
  const float* mask = (const float*)d_in[1];
  const float* qw   = (const float*)d_in[2];
  const float* qb   = (const float*)d_in[3];
  const float* kw   = (const float*)d_in[4];
  const float* kb   = (const float*)d_in[5];
  const float* vw   = (const float*)d_in[6];
  const float* vb   = (const float*)d_in[7];
  const float* pw   = (const float*)d_in[8];
  const float* pb   = (const float*)d_in[9];
  const float* w1   = (const float*)d_in[10];
  const float* b1   = (const float*)d_in[11];
  const float* w2   = (const float*)d_in[12];
  const float* ls   = (const float*)d_in[13];
  const float* tbl  = (const float*)d_in[14];
  const int*   rpi  = (const int*)d_in[15];
  float* out = (float*)d_out;

  k_prep_a<<<9, 256, 0, stream>>>(qw, kw, vw, pw, tbl, w1, b1, w2, ls);
  k_prep2<<<2048, 256, 0, stream>>>(mask, rpi);
  k_main<<<B_ * 2, 512, 0, stream>>>(x, out, qb, kb, vb, pb);
}